// Round 7
// baseline (270.895 us; speedup 1.0000x reference)
//
#include <hip/hip_runtime.h>

#define HW    96
#define NPIX  9216        // 96*96
#define NCH   64          // C
#define INNER 3
#define NDIL  3
#define BB    2           // batch
#define TOTPIX (BB * NPIX)   // 18432

typedef __attribute__((ext_vector_type(8))) short short8;            // 8 bf16
typedef __attribute__((ext_vector_type(8))) unsigned short ushort8;  // 8 bf16 raw
typedef __attribute__((ext_vector_type(4))) float f32x4;

__device__ __forceinline__ ushort f2bf_rne(float f) {
    unsigned u = __float_as_uint(f);
    u += 0x7fffu + ((u >> 16) & 1u);
    return (ushort)(u >> 16);
}
__device__ __forceinline__ float bf2f(ushort u) {
    return __uint_as_float((unsigned)u << 16);
}
// pack hi16(a),hi16(b) -> dword {bf16(b)<<16 | bf16(a)} (trunc; ratio-safe for P)
__device__ __forceinline__ unsigned pack_bf(float lo, float hi) {
    return __builtin_amdgcn_perm(__float_as_uint(hi), __float_as_uint(lo), 0x07060302u);
}

// ---------------------------------------------------------------------------
// Kernel 1: x_red = 1x1 conv (64 -> 3 channels)
// ---------------------------------------------------------------------------
__global__ void k_reduce(const float* __restrict__ x, const float* __restrict__ w_red,
                         const float* __restrict__ b_red, float* __restrict__ xred) {
    int pix = blockIdx.x * blockDim.x + threadIdx.x;
    if (pix >= TOTPIX) return;
    int b = pix / NPIX, n = pix % NPIX;
    float a0 = b_red[0], a1 = b_red[1], a2 = b_red[2];
    const float* xb = x + (size_t)b * NCH * NPIX + n;
    #pragma unroll
    for (int c = 0; c < NCH; ++c) {
        float xv = xb[(size_t)c * NPIX];
        a0 = fmaf(w_red[0 * NCH + c], xv, a0);
        a1 = fmaf(w_red[1 * NCH + c], xv, a1);
        a2 = fmaf(w_red[2 * NCH + c], xv, a2);
    }
    float* xr = xred + (size_t)b * INNER * NPIX + n;
    xr[0 * NPIX] = a0; xr[1 * NPIX] = a1; xr[2 * NPIX] = a2;
}

// ---------------------------------------------------------------------------
// Kernel 2a: features. thread = (pixel, dilation i3). Conv taps + 4/6
// transforms are coalesced across threads (consecutive pixels). Writes
// FT[j][pix] bf16, j = i3*18 + t*3 + o (coalesced per j). Rows 54..63 of FT
// are never written (poison) — zero-weighted in k_fuse's padded W.
// ---------------------------------------------------------------------------
__global__ __launch_bounds__(256) void
k_feat(const float* __restrict__ xred, const float* __restrict__ w_dil,
       const float* __restrict__ b_dil, ushort* __restrict__ FT) {
    int gid = blockIdx.x * 256 + threadIdx.x;      // 3 * 18432 threads
    int i3 = gid / TOTPIX;                          // wave-uniform (18432 % 64 == 0)
    int pix = gid - i3 * TOTPIX;
    int b = pix / NPIX, n = pix % NPIX;
    int h = n / HW, w = n % HW;
    const float* xr = xred + (size_t)b * INNER * NPIX;
    int d = i3 + 1;

    float co[3] = {b_dil[i3 * 3 + 0], b_dil[i3 * 3 + 1], b_dil[i3 * 3 + 2]};
    #pragma unroll
    for (int ci = 0; ci < 3; ++ci) {
        const float* xo = xr + ci * NPIX;
        #pragma unroll
        for (int kh = 0; kh < 3; ++kh) {
            int hh = h + (kh - 1) * d;
            #pragma unroll
            for (int kw = 0; kw < 3; ++kw) {
                int ww = w + (kw - 1) * d;
                float v = ((unsigned)hh < HW && (unsigned)ww < HW) ? xo[hh * HW + ww] : 0.f;
                #pragma unroll
                for (int o = 0; o < 3; ++o)     // w_dil idx wave-uniform -> scalar loads
                    co[o] = fmaf(w_dil[(9 * i3 + 3 * o + ci) * 9 + kh * 3 + kw], v, co[o]);
            }
        }
    }

    float tf[6][3];
    #pragma unroll
    for (int o = 0; o < 3; ++o) {
        const float* xo = xr + o * NPIX;
        tf[0][o] = xo[h * HW + w];
        tf[1][o] = xo[h * HW + (HW - 1 - w)];
        tf[2][o] = xo[(HW - 1 - h) * HW + w];
        tf[3][o] = xo[w * HW + (HW - 1 - h)];
        tf[4][o] = xo[(HW - 1 - h) * HW + (HW - 1 - w)];
        tf[5][o] = xo[(HW - 1 - w) * HW + h];
    }

    #pragma unroll
    for (int t = 0; t < 6; ++t)
        #pragma unroll
        for (int o = 0; o < 3; ++o) {
            int j = i3 * 18 + t * 3 + o;
            FT[(size_t)j * TOTPIX + pix] = f2bf_rne(co[o] * tf[t][o]);
        }
}

// ---------------------------------------------------------------------------
// Kernel 2b: fuse conv as MFMA GEMM: tokD[c][px] = sum_j Wpad[c][j]*FT[j][px]
// + bias. Wpad is w_fuse zero-padded to K=64 (bf16, LDS). Block = 256 px,
// 4 waves x 64 px each, all 64 ch. Epilogue: LDS transpose tile -> coalesced
// writes of both tok[b][n][c] and tokT[b][c][n].
// ---------------------------------------------------------------------------
__global__ __launch_bounds__(256) void
k_fuse(const ushort* __restrict__ FT, const float* __restrict__ w_fuse,
       const float* __restrict__ b_fuse, ushort* __restrict__ tok,
       ushort* __restrict__ tokT) {
    __shared__ ushort wpad[64 * 72];     // [c][j pad 72] (144B rows: 16B-aligned, 2-way banks)
    __shared__ float  bsh[64];
    __shared__ ushort tile[64 * 266];    // [c][px 256 + 10 pad] (stride 133 dw, odd)

    int tid = threadIdx.x;
    for (int i = tid; i < 64 * 64; i += 256) {
        int c = i >> 6, j = i & 63;
        wpad[c * 72 + j] = (j < 54) ? f2bf_rne(w_fuse[c * 54 + j]) : (ushort)0;
    }
    if (tid < 64) bsh[tid] = b_fuse[tid];
    __syncthreads();

    int wv = tid >> 6, lane = tid & 63, quad = lane >> 4, l15 = lane & 15;
    int px0 = blockIdx.x * 256;

    short8 af[4][2];                     // A[m=c][k=j]
    #pragma unroll
    for (int m = 0; m < 4; ++m)
        #pragma unroll
        for (int kc = 0; kc < 2; ++kc)
            af[m][kc] = *(const short8*)&wpad[(16 * m + l15) * 72 + quad * 8 + 32 * kc];

    f32x4 acc[4][4];                     // [m=c-tile][nn=px-tile]
    #pragma unroll
    for (int m = 0; m < 4; ++m)
        #pragma unroll
        for (int nn = 0; nn < 4; ++nn) acc[m][nn] = (f32x4){0.f, 0.f, 0.f, 0.f};

    #pragma unroll
    for (int nn = 0; nn < 4; ++nn) {
        int px = px0 + wv * 64 + nn * 16 + l15;
        #pragma unroll
        for (int kc = 0; kc < 2; ++kc) {
            short8 bf;
            #pragma unroll
            for (int jj = 0; jj < 8; ++jj)
                bf[jj] = (short)FT[(size_t)(quad * 8 + jj + 32 * kc) * TOTPIX + px];
            #pragma unroll
            for (int m = 0; m < 4; ++m)
                acc[m][nn] = __builtin_amdgcn_mfma_f32_16x16x32_bf16(af[m][kc], bf,
                                                                     acc[m][nn], 0, 0, 0);
        }
    }

    #pragma unroll
    for (int m = 0; m < 4; ++m) {
        #pragma unroll
        for (int r = 0; r < 4; ++r) {
            int c = 16 * m + quad * 4 + r;
            float bv = bsh[c];
            #pragma unroll
            for (int nn = 0; nn < 4; ++nn)
                tile[c * 266 + wv * 64 + nn * 16 + l15] = f2bf_rne(acc[m][nn][r] + bv);
        }
    }
    __syncthreads();

    {   // tok[b][n][c]: thread = one pixel, gathers its channel column
        int px = px0 + tid;
        int bb = px / NPIX, nn = px % NPIX;
        ushort row[64];
        #pragma unroll
        for (int c = 0; c < 64; ++c) row[c] = tile[c * 266 + tid];
        ushort* dst = tok + ((size_t)bb * NPIX + nn) * NCH;
        #pragma unroll
        for (int k = 0; k < 8; ++k)
            *(ushort8*)&dst[k * 8] = *(const ushort8*)&row[k * 8];
    }
    {   // tokT[b][c][n]: thread = (c, 64-px segment), contiguous both sides
        int c = tid >> 2, seg = tid & 3;
        int px = px0 + seg * 64;         // 256-px block never straddles batch
        int bb = px / NPIX, nn = px % NPIX;
        ushort* dst = tokT + ((size_t)bb * NCH + c) * NPIX + nn;
        #pragma unroll
        for (int k = 0; k < 8; ++k)
            *(ushort8*)&dst[k * 8] = *(const ushort8*)&tile[c * 266 + seg * 64 + k * 8];
    }
}

// ---------------------------------------------------------------------------
// Kernel 3: MFMA flash attention partials, transposed form, 32 queries/wave.
// S^T = K·Q^T (per-col softmax, per-lane scalar), O^T = V^T·P^T. No K/V LDS
// staging, no barriers (frags direct from tok/tokT, L1/L2-resident). Fixed
// exp2 base FM=16 (softmax shift-invariant; no running max / rescale / pm).
// Per-wave P^T tile [32][40] (80B rows: <=2-way banks). pacc bf16.
// 32q/wave halves accumulator state -> ~110 total regs -> 4 waves/SIMD.
// ---------------------------------------------------------------------------
__global__ __launch_bounds__(256, 4) void
k_attn(const ushort* __restrict__ tok, const ushort* __restrict__ tokT,
       float* __restrict__ pl, ushort* __restrict__ pacc, int P, int KP) {
    __shared__ ushort pt[4][32 * 40];   // per-wave P^T [q][32key + 8 pad], 10 KB

    const int QW = NPIX / 128;          // 72 query chunks per batch
    int bid = blockIdx.x;
    int qc = bid % QW; int rest = bid / QW;
    int p = rest % P;  int b = rest / P;
    int tid = threadIdx.x;
    int wv = tid >> 6, lane = tid & 63;
    int quad = lane >> 4, l15 = lane & 15;

    const ushort* tb  = tok  + (size_t)b * NPIX * NCH;
    const ushort* tbT = tokT + (size_t)b * NCH * NPIX;
    int qwave = qc * 128 + wv * 32;

    // Q fragments: B operand of S^T (lane n=l15, k=quad*8+j+32kc); scale folded.
    short8 qf[2][2];
    const float scale = 0.125f * 1.44269504088896340736f;  // 1/sqrt(C) * log2(e)
    #pragma unroll
    for (int n = 0; n < 2; ++n) {
        const ushort* qr = tb + (size_t)(qwave + 16 * n + l15) * NCH + quad * 8;
        #pragma unroll
        for (int kc = 0; kc < 2; ++kc) {
            ushort8 raw = *(const ushort8*)(qr + 32 * kc);
            short8 f;
            #pragma unroll
            for (int e = 0; e < 8; ++e) f[e] = (short)f2bf_rne(bf2f(raw[e]) * scale);
            qf[n][kc] = f;
        }
    }

    f32x4 O[4][2];                      // O^T acc: D[c=16m+quad*4+reg][q=16n+l15]
    #pragma unroll
    for (int m = 0; m < 4; ++m)
        #pragma unroll
        for (int n = 0; n < 2; ++n) O[m][n] = (f32x4){0.f, 0.f, 0.f, 0.f};
    float lrun[2] = {0.f, 0.f};

    const float FM = 16.0f;             // fixed exp2-domain shift

    int k0 = p * KP;
    for (int kb = 0; kb < KP; kb += 32) {
        int kbase = k0 + kb;

        // S^T 32-key step: D[key][q]; A rows (keys) direct from tok
        f32x4 S[2][2];
        #pragma unroll
        for (int m = 0; m < 2; ++m)
            #pragma unroll
            for (int n = 0; n < 2; ++n) S[m][n] = (f32x4){0.f, 0.f, 0.f, 0.f};
        #pragma unroll
        for (int m2 = 0; m2 < 2; ++m2) {
            const ushort* kr = tb + (size_t)(kbase + 16 * m2 + l15) * NCH + quad * 8;
            #pragma unroll
            for (int kc = 0; kc < 2; ++kc) {
                short8 kf = *(const short8*)(kr + 32 * kc);
                #pragma unroll
                for (int n = 0; n < 2; ++n)
                    S[m2][n] = __builtin_amdgcn_mfma_f32_16x16x32_bf16(kf, qf[n][kc],
                                                                       S[m2][n], 0, 0, 0);
            }
        }

        // V^T fragments (A[ch][key]) direct from tokT
        short8 vf[4];
        #pragma unroll
        for (int mc = 0; mc < 4; ++mc)
            vf[mc] = *(const short8*)(tbT + (size_t)(16 * mc + l15) * NPIX + kbase + quad * 8);

        // softmax numerators, fixed base: p = exp2(s - FM)
        #pragma unroll
        for (int n = 0; n < 2; ++n) {
            int q = 16 * n + l15;
            #pragma unroll
            for (int m2 = 0; m2 < 2; ++m2) {
                float p0 = __builtin_amdgcn_exp2f(S[m2][n][0] - FM);
                float p1 = __builtin_amdgcn_exp2f(S[m2][n][1] - FM);
                float p2 = __builtin_amdgcn_exp2f(S[m2][n][2] - FM);
                float p3 = __builtin_amdgcn_exp2f(S[m2][n][3] - FM);
                lrun[n] += (p0 + p1) + (p2 + p3);
                uint2 wd = make_uint2(pack_bf(p0, p1), pack_bf(p2, p3));
                // key_local = 16*m2 + quad*4 + reg
                *(uint2*)&pt[wv][q * 40 + m2 * 16 + quad * 4] = wd;
            }
        }

        // O^T += V^T·P^T (K=32): B[k=quad*8+j][n=q] from padded pt (same wave)
        #pragma unroll
        for (int n = 0; n < 2; ++n) {
            int q = 16 * n + l15;
            short8 bfr = *(const short8*)&pt[wv][q * 40 + quad * 8];
            #pragma unroll
            for (int mc = 0; mc < 4; ++mc)
                O[mc][n] = __builtin_amdgcn_mfma_f32_16x16x32_bf16(vf[mc], bfr,
                                                                   O[mc][n], 0, 0, 0);
        }
    }

    #pragma unroll
    for (int n = 0; n < 2; ++n) {       // disjoint key subsets per quad
        lrun[n] += __shfl_xor(lrun[n], 16, 64);
        lrun[n] += __shfl_xor(lrun[n], 32, 64);
    }
    size_t bpb = ((size_t)b * P + p) * NPIX;
    if (quad == 0) {
        #pragma unroll
        for (int n = 0; n < 2; ++n)
            pl[bpb + qwave + 16 * n + l15] = lrun[n];
    }
    #pragma unroll
    for (int n = 0; n < 2; ++n) {
        int qg = qwave + 16 * n + l15;
        ushort* dst = pacc + (bpb + qg) * NCH;
        #pragma unroll
        for (int m = 0; m < 4; ++m) {
            uint2 wd = make_uint2(
                __builtin_amdgcn_perm(__float_as_uint(O[m][n][1]) + 0x8000u,
                                      __float_as_uint(O[m][n][0]) + 0x8000u, 0x07060302u),
                __builtin_amdgcn_perm(__float_as_uint(O[m][n][3]) + 0x8000u,
                                      __float_as_uint(O[m][n][2]) + 0x8000u, 0x07060302u));
            *(uint2*)(dst + 16 * m + quad * 4) = wd;
        }
    }
}

// ---------------------------------------------------------------------------
// Kernel 4: merge P partials — pure sum (shared fixed exp2 base) + residual.
// pacc is bf16. out = x + 0.2*attn (NCHW). 8 channels/thread.
// ---------------------------------------------------------------------------
__global__ void k_combine(const float* __restrict__ x, const float* __restrict__ pl,
                          const ushort* __restrict__ pacc, float* __restrict__ out,
                          int P) {
    int gid = blockIdx.x * blockDim.x + threadIdx.x;
    if (gid >= TOTPIX * 8) return;
    int pix = gid >> 3, cq = gid & 7;
    int b = pix / NPIX, n = pix % NPIX;
    int c0 = cq * 8;
    float L = 0.f;
    float o[8];
    #pragma unroll
    for (int i = 0; i < 8; ++i) o[i] = 0.f;
    for (int p = 0; p < P; ++p) {
        size_t base = ((size_t)b * P + p) * NPIX + n;
        L += pl[base];
        ushort8 t = *(const ushort8*)(pacc + base * NCH + c0);
        #pragma unroll
        for (int e = 0; e < 8; ++e)
            o[e] += bf2f(t[e]);
    }
    float inv = 0.2f / L;
    const float* xb = x + ((size_t)b * NCH + c0) * NPIX + n;
    float* ob = out + ((size_t)b * NCH + c0) * NPIX + n;
    #pragma unroll
    for (int i = 0; i < 8; ++i)
        ob[(size_t)i * NPIX] = fmaf(inv, o[i], xb[(size_t)i * NPIX]);
}

// ---------------------------------------------------------------------------
extern "C" void kernel_launch(void* const* d_in, const int* in_sizes, int n_in,
                              void* d_out, int out_size, void* d_ws, size_t ws_size,
                              hipStream_t stream) {
    const float* x      = (const float*)d_in[0];
    const float* w_red  = (const float*)d_in[1];
    const float* b_red  = (const float*)d_in[2];
    const float* w_dil  = (const float*)d_in[3];
    const float* b_dil  = (const float*)d_in[4];
    const float* w_fuse = (const float*)d_in[5];
    const float* b_fuse = (const float*)d_in[6];
    float* out = (float*)d_out;

    // ws layout: xred f32 | FT bf16(64 rows) | tok bf16 | tokT bf16 | pl f32 | pacc bf16
    const size_t XRED_N = (size_t)BB * INNER * NPIX;     //    55,296 f32
    const size_t FT_N   = (size_t)64 * TOTPIX;           // 1,179,648 bf16
    const size_t TOK_N  = (size_t)BB * NPIX * NCH;       // 1,179,648 bf16 (x2 layouts)
    const size_t HEAD_B = XRED_N * 4 + (FT_N + 2 * TOK_N) * 2;
    int P = 0;
    const int cands[5] = {16, 8, 4, 2, 1};               // KP=9216/P mult of 32 for all
    for (int ci = 0; ci < 5; ++ci) {
        int cp = cands[ci];
        size_t need = HEAD_B + (size_t)BB * cp * NPIX * (4 + NCH * 2);
        if (ws_size >= need) { P = cp; break; }
    }
    if (P == 0) return;

    float*  xred = (float*)d_ws;
    ushort* FT   = (ushort*)(xred + XRED_N);
    ushort* tok  = FT + FT_N;
    ushort* tokT = tok + TOK_N;
    float*  pl   = (float*)(tokT + TOK_N);
    ushort* pacc = (ushort*)(pl + (size_t)BB * P * NPIX);

    k_reduce <<<(TOTPIX + 255) / 256, 256, 0, stream>>>(x, w_red, b_red, xred);
    k_feat   <<<3 * TOTPIX / 256, 256, 0, stream>>>(xred, w_dil, b_dil, FT);
    k_fuse   <<<TOTPIX / 256, 256, 0, stream>>>(FT, w_fuse, b_fuse, tok, tokT);
    k_attn   <<<BB * P * (NPIX / 128), 256, 0, stream>>>(tok, tokT, pl, pacc,
                                                         P, NPIX / P);
    k_combine<<<(TOTPIX * 8 + 255) / 256, 256, 0, stream>>>(x, pl, pacc, out, P);
}

// Round 8
// 201.283 us; speedup vs baseline: 1.3458x; 1.3458x over previous
//
#include <hip/hip_runtime.h>

#define HW    96
#define NPIX  9216        // 96*96
#define NCH   64          // C
#define INNER 3
#define NDIL  3
#define BB    2           // batch
#define TOTPIX (BB * NPIX)   // 18432

typedef __attribute__((ext_vector_type(8))) short short8;            // 8 bf16
typedef __attribute__((ext_vector_type(8))) unsigned short ushort8;  // 8 bf16 raw
typedef __attribute__((ext_vector_type(4))) float f32x4;

__device__ __forceinline__ ushort f2bf_rne(float f) {
    unsigned u = __float_as_uint(f);
    u += 0x7fffu + ((u >> 16) & 1u);
    return (ushort)(u >> 16);
}
__device__ __forceinline__ float bf2f(ushort u) {
    return __uint_as_float((unsigned)u << 16);
}
// pack hi16(a),hi16(b) -> dword {bf16(b)<<16 | bf16(a)} (trunc; ratio-safe for P)
__device__ __forceinline__ unsigned pack_bf(float lo, float hi) {
    return __builtin_amdgcn_perm(__float_as_uint(hi), __float_as_uint(lo), 0x07060302u);
}

// ---------------------------------------------------------------------------
// Kernel 1: x_red = 1x1 conv (64 -> 3 channels)
// ---------------------------------------------------------------------------
__global__ void k_reduce(const float* __restrict__ x, const float* __restrict__ w_red,
                         const float* __restrict__ b_red, float* __restrict__ xred) {
    int pix = blockIdx.x * blockDim.x + threadIdx.x;
    if (pix >= TOTPIX) return;
    int b = pix / NPIX, n = pix % NPIX;
    float a0 = b_red[0], a1 = b_red[1], a2 = b_red[2];
    const float* xb = x + (size_t)b * NCH * NPIX + n;
    #pragma unroll
    for (int c = 0; c < NCH; ++c) {
        float xv = xb[(size_t)c * NPIX];
        a0 = fmaf(w_red[0 * NCH + c], xv, a0);
        a1 = fmaf(w_red[1 * NCH + c], xv, a1);
        a2 = fmaf(w_red[2 * NCH + c], xv, a2);
    }
    float* xr = xred + (size_t)b * INNER * NPIX + n;
    xr[0 * NPIX] = a0; xr[1 * NPIX] = a1; xr[2 * NPIX] = a2;
}

// ---------------------------------------------------------------------------
// Kernel 2a: features. thread = (pixel, dilation i3). Conv taps + transforms
// mostly coalesced. Writes FT[j][pix] bf16, j = i3*18 + t*3 + o. Rows 54..63
// never written (poison) — zero-weighted in k_fuse's padded W.
// ---------------------------------------------------------------------------
__global__ __launch_bounds__(256) void
k_feat(const float* __restrict__ xred, const float* __restrict__ w_dil,
       const float* __restrict__ b_dil, ushort* __restrict__ FT) {
    int gid = blockIdx.x * 256 + threadIdx.x;      // 3 * 18432 threads
    int i3 = gid / TOTPIX;                          // wave-uniform (18432 % 64 == 0)
    int pix = gid - i3 * TOTPIX;
    int b = pix / NPIX, n = pix % NPIX;
    int h = n / HW, w = n % HW;
    const float* xr = xred + (size_t)b * INNER * NPIX;
    int d = i3 + 1;

    float co[3] = {b_dil[i3 * 3 + 0], b_dil[i3 * 3 + 1], b_dil[i3 * 3 + 2]};
    #pragma unroll
    for (int ci = 0; ci < 3; ++ci) {
        const float* xo = xr + ci * NPIX;
        #pragma unroll
        for (int kh = 0; kh < 3; ++kh) {
            int hh = h + (kh - 1) * d;
            #pragma unroll
            for (int kw = 0; kw < 3; ++kw) {
                int ww = w + (kw - 1) * d;
                float v = ((unsigned)hh < HW && (unsigned)ww < HW) ? xo[hh * HW + ww] : 0.f;
                #pragma unroll
                for (int o = 0; o < 3; ++o)     // w_dil idx wave-uniform -> scalar loads
                    co[o] = fmaf(w_dil[(9 * i3 + 3 * o + ci) * 9 + kh * 3 + kw], v, co[o]);
            }
        }
    }

    float tf[6][3];
    #pragma unroll
    for (int o = 0; o < 3; ++o) {
        const float* xo = xr + o * NPIX;
        tf[0][o] = xo[h * HW + w];
        tf[1][o] = xo[h * HW + (HW - 1 - w)];
        tf[2][o] = xo[(HW - 1 - h) * HW + w];
        tf[3][o] = xo[w * HW + (HW - 1 - h)];
        tf[4][o] = xo[(HW - 1 - h) * HW + (HW - 1 - w)];
        tf[5][o] = xo[(HW - 1 - w) * HW + h];
    }

    #pragma unroll
    for (int t = 0; t < 6; ++t)
        #pragma unroll
        for (int o = 0; o < 3; ++o) {
            int j = i3 * 18 + t * 3 + o;
            FT[(size_t)j * TOTPIX + pix] = f2bf_rne(co[o] * tf[t][o]);
        }
}

// ---------------------------------------------------------------------------
// Kernel 2b: fuse conv as MFMA GEMM, 64 px/block (grid 288 fills all CUs).
// tokD[c][px] = sum_j Wpad[c][j]*FT[j][px] + bias; Wpad zero-padded to K=64.
// 4 waves x 16 px each. Epilogue via LDS tile -> tok[b][n][c] + tokT[b][c][n].
// ---------------------------------------------------------------------------
__global__ __launch_bounds__(256) void
k_fuse(const ushort* __restrict__ FT, const float* __restrict__ w_fuse,
       const float* __restrict__ b_fuse, ushort* __restrict__ tok,
       ushort* __restrict__ tokT) {
    __shared__ ushort wpad[64 * 72];     // [c][j pad 72]
    __shared__ float  bsh[64];
    __shared__ ushort tile[64 * 72];     // [c][64 px + 8 pad]

    int tid = threadIdx.x;
    for (int i = tid; i < 64 * 64; i += 256) {
        int c = i >> 6, j = i & 63;
        wpad[c * 72 + j] = (j < 54) ? f2bf_rne(w_fuse[c * 54 + j]) : (ushort)0;
    }
    if (tid < 64) bsh[tid] = b_fuse[tid];
    __syncthreads();

    int wv = tid >> 6, lane = tid & 63, quad = lane >> 4, l15 = lane & 15;
    int px0 = blockIdx.x * 64;           // never straddles batch (NPIX % 64 == 0)

    short8 af[4][2];                     // A[m=c][k=j]
    #pragma unroll
    for (int m = 0; m < 4; ++m)
        #pragma unroll
        for (int kc = 0; kc < 2; ++kc)
            af[m][kc] = *(const short8*)&wpad[(16 * m + l15) * 72 + quad * 8 + 32 * kc];

    f32x4 acc[4];                        // [m=c-tile]; this wave's 16 px
    #pragma unroll
    for (int m = 0; m < 4; ++m) acc[m] = (f32x4){0.f, 0.f, 0.f, 0.f};

    int px = px0 + wv * 16 + l15;
    #pragma unroll
    for (int kc = 0; kc < 2; ++kc) {
        short8 bf;
        #pragma unroll
        for (int jj = 0; jj < 8; ++jj)
            bf[jj] = (short)FT[(size_t)(quad * 8 + jj + 32 * kc) * TOTPIX + px];
        #pragma unroll
        for (int m = 0; m < 4; ++m)
            acc[m] = __builtin_amdgcn_mfma_f32_16x16x32_bf16(af[m][kc], bf, acc[m], 0, 0, 0);
    }

    #pragma unroll
    for (int m = 0; m < 4; ++m)
        #pragma unroll
        for (int r = 0; r < 4; ++r) {
            int c = 16 * m + quad * 4 + r;
            tile[c * 72 + wv * 16 + l15] = f2bf_rne(acc[m][r] + bsh[c]);
        }
    __syncthreads();

    int b0 = px0 / NPIX, n0 = px0 % NPIX;
    {   // tok[b][n][c]: thread = (px, 16-ch part)
        int lp = tid >> 2, part = tid & 3;
        ushort row[16];
        #pragma unroll
        for (int k = 0; k < 16; ++k) row[k] = tile[(part * 16 + k) * 72 + lp];
        ushort* dst = tok + ((size_t)b0 * NPIX + n0 + lp) * NCH + part * 16;
        *(ushort8*)&dst[0] = *(const ushort8*)&row[0];
        *(ushort8*)&dst[8] = *(const ushort8*)&row[8];
    }
    {   // tokT[b][c][n]: thread = (c, 16-px segment), contiguous both sides
        int c = tid >> 2, seg = tid & 3;
        ushort* dst = tokT + ((size_t)b0 * NCH + c) * NPIX + n0 + seg * 16;
        *(ushort8*)&dst[0] = *(const ushort8*)&tile[c * 72 + seg * 16];
        *(ushort8*)&dst[8] = *(const ushort8*)&tile[c * 72 + seg * 16 + 8];
    }
}

// ---------------------------------------------------------------------------
// Kernel 3: MFMA flash attention partials, transposed form, 64 queries/wave
// (R6 tile = good reuse), restructured PER n-TILE to cut register liveness:
// per 32-key step: load kf[2][2]+vf[4] once; for each 16-query group n:
// 4 S-MFMA -> softmax (fixed exp2 base FM, shift-invariant) -> pt -> 4 O-MFMA.
// Peak live ~145 regs -> launch_bounds(256,3) = 12 waves/CU (R6 had 8).
// No K/V LDS staging, no barriers. pt rows padded to 80 B. pacc bf16.
// ---------------------------------------------------------------------------
__global__ __launch_bounds__(256, 3) void
k_attn(const ushort* __restrict__ tok, const ushort* __restrict__ tokT,
       float* __restrict__ pl, ushort* __restrict__ pacc, int P, int KP) {
    __shared__ ushort pt[4][64 * 40];   // per-wave P^T [q][32key + 8 pad], 20 KB

    const int QW = NPIX / 256;          // 36 query chunks per batch
    int bid = blockIdx.x;
    int qc = bid % QW; int rest = bid / QW;
    int p = rest % P;  int b = rest / P;
    int tid = threadIdx.x;
    int wv = tid >> 6, lane = tid & 63;
    int quad = lane >> 4, l15 = lane & 15;

    const ushort* tb  = tok  + (size_t)b * NPIX * NCH;
    const ushort* tbT = tokT + (size_t)b * NCH * NPIX;
    int qwave = qc * 256 + wv * 64;

    // Q fragments: B operand of S^T (lane n=l15, k=quad*8+j+32kc); scale folded.
    short8 qf[4][2];
    const float scale = 0.125f * 1.44269504088896340736f;  // 1/sqrt(C) * log2(e)
    #pragma unroll
    for (int n = 0; n < 4; ++n) {
        const ushort* qr = tb + (size_t)(qwave + 16 * n + l15) * NCH + quad * 8;
        #pragma unroll
        for (int kc = 0; kc < 2; ++kc) {
            ushort8 raw = *(const ushort8*)(qr + 32 * kc);
            short8 f;
            #pragma unroll
            for (int e = 0; e < 8; ++e) f[e] = (short)f2bf_rne(bf2f(raw[e]) * scale);
            qf[n][kc] = f;
        }
    }

    f32x4 O[4][4];                      // O^T acc: D[c=16m+quad*4+reg][q=16n+l15]
    #pragma unroll
    for (int m = 0; m < 4; ++m)
        #pragma unroll
        for (int n = 0; n < 4; ++n) O[m][n] = (f32x4){0.f, 0.f, 0.f, 0.f};
    float lrun[4] = {0.f, 0.f, 0.f, 0.f};

    const float FM = 16.0f;             // fixed exp2-domain shift

    int k0 = p * KP;
    for (int kb = 0; kb < KP; kb += 32) {
        int kbase = k0 + kb;

        // K fragments (A[key][ch]) and V^T fragments (A[ch][key]) — loaded
        // once per step, reused by all 4 query groups.
        short8 kf[2][2];
        #pragma unroll
        for (int m2 = 0; m2 < 2; ++m2) {
            const ushort* kr = tb + (size_t)(kbase + 16 * m2 + l15) * NCH + quad * 8;
            kf[m2][0] = *(const short8*)(kr);
            kf[m2][1] = *(const short8*)(kr + 32);
        }
        short8 vf[4];
        #pragma unroll
        for (int mc = 0; mc < 4; ++mc)
            vf[mc] = *(const short8*)(tbT + (size_t)(16 * mc + l15) * NPIX + kbase + quad * 8);

        #pragma unroll
        for (int n = 0; n < 4; ++n) {
            f32x4 s0 = (f32x4){0.f, 0.f, 0.f, 0.f};
            f32x4 s1 = (f32x4){0.f, 0.f, 0.f, 0.f};
            s0 = __builtin_amdgcn_mfma_f32_16x16x32_bf16(kf[0][0], qf[n][0], s0, 0, 0, 0);
            s0 = __builtin_amdgcn_mfma_f32_16x16x32_bf16(kf[0][1], qf[n][1], s0, 0, 0, 0);
            s1 = __builtin_amdgcn_mfma_f32_16x16x32_bf16(kf[1][0], qf[n][0], s1, 0, 0, 0);
            s1 = __builtin_amdgcn_mfma_f32_16x16x32_bf16(kf[1][1], qf[n][1], s1, 0, 0, 0);

            int q = 16 * n + l15;
            float p0 = __builtin_amdgcn_exp2f(s0[0] - FM);
            float p1 = __builtin_amdgcn_exp2f(s0[1] - FM);
            float p2 = __builtin_amdgcn_exp2f(s0[2] - FM);
            float p3 = __builtin_amdgcn_exp2f(s0[3] - FM);
            float p4 = __builtin_amdgcn_exp2f(s1[0] - FM);
            float p5 = __builtin_amdgcn_exp2f(s1[1] - FM);
            float p6 = __builtin_amdgcn_exp2f(s1[2] - FM);
            float p7 = __builtin_amdgcn_exp2f(s1[3] - FM);
            lrun[n] += ((p0 + p1) + (p2 + p3)) + ((p4 + p5) + (p6 + p7));
            *(uint2*)&pt[wv][q * 40 + quad * 4]      = make_uint2(pack_bf(p0, p1), pack_bf(p2, p3));
            *(uint2*)&pt[wv][q * 40 + 16 + quad * 4] = make_uint2(pack_bf(p4, p5), pack_bf(p6, p7));

            short8 bfr = *(const short8*)&pt[wv][q * 40 + quad * 8];
            #pragma unroll
            for (int mc = 0; mc < 4; ++mc)
                O[mc][n] = __builtin_amdgcn_mfma_f32_16x16x32_bf16(vf[mc], bfr,
                                                                   O[mc][n], 0, 0, 0);
        }
    }

    #pragma unroll
    for (int n = 0; n < 4; ++n) {       // disjoint key subsets per quad
        lrun[n] += __shfl_xor(lrun[n], 16, 64);
        lrun[n] += __shfl_xor(lrun[n], 32, 64);
    }
    size_t bpb = ((size_t)b * P + p) * NPIX;
    if (quad == 0) {
        #pragma unroll
        for (int n = 0; n < 4; ++n)
            pl[bpb + qwave + 16 * n + l15] = lrun[n];
    }
    #pragma unroll
    for (int n = 0; n < 4; ++n) {
        int qg = qwave + 16 * n + l15;
        ushort* dst = pacc + (bpb + qg) * NCH;
        #pragma unroll
        for (int m = 0; m < 4; ++m) {
            uint2 wd = make_uint2(
                __builtin_amdgcn_perm(__float_as_uint(O[m][n][1]) + 0x8000u,
                                      __float_as_uint(O[m][n][0]) + 0x8000u, 0x07060302u),
                __builtin_amdgcn_perm(__float_as_uint(O[m][n][3]) + 0x8000u,
                                      __float_as_uint(O[m][n][2]) + 0x8000u, 0x07060302u));
            *(uint2*)(dst + 16 * m + quad * 4) = wd;
        }
    }
}

// ---------------------------------------------------------------------------
// Kernel 4: merge P partials — pure sum (shared fixed exp2 base) + residual.
// 4 channels/thread -> grid 1152 (latency hiding for the P strided reads).
// ---------------------------------------------------------------------------
__global__ void k_combine(const float* __restrict__ x, const float* __restrict__ pl,
                          const ushort* __restrict__ pacc, float* __restrict__ out,
                          int P) {
    int gid = blockIdx.x * blockDim.x + threadIdx.x;
    if (gid >= TOTPIX * 16) return;
    int pix = gid >> 4, cg = gid & 15;
    int b = pix / NPIX, n = pix % NPIX;
    int c0 = cg * 4;
    float L = 0.f;
    float o[4] = {0.f, 0.f, 0.f, 0.f};
    for (int p = 0; p < P; ++p) {
        size_t base = ((size_t)b * P + p) * NPIX + n;
        L += pl[base];
        ushort4 t = *(const ushort4*)(pacc + base * NCH + c0);
        o[0] += bf2f(t.x); o[1] += bf2f(t.y);
        o[2] += bf2f(t.z); o[3] += bf2f(t.w);
    }
    float inv = 0.2f / L;
    const float* xb = x + ((size_t)b * NCH + c0) * NPIX + n;
    float* ob = out + ((size_t)b * NCH + c0) * NPIX + n;
    #pragma unroll
    for (int i = 0; i < 4; ++i)
        ob[(size_t)i * NPIX] = fmaf(inv, o[i], xb[(size_t)i * NPIX]);
}

// ---------------------------------------------------------------------------
extern "C" void kernel_launch(void* const* d_in, const int* in_sizes, int n_in,
                              void* d_out, int out_size, void* d_ws, size_t ws_size,
                              hipStream_t stream) {
    const float* x      = (const float*)d_in[0];
    const float* w_red  = (const float*)d_in[1];
    const float* b_red  = (const float*)d_in[2];
    const float* w_dil  = (const float*)d_in[3];
    const float* b_dil  = (const float*)d_in[4];
    const float* w_fuse = (const float*)d_in[5];
    const float* b_fuse = (const float*)d_in[6];
    float* out = (float*)d_out;

    // ws layout: xred f32 | FT bf16(64 rows) | tok bf16 | tokT bf16 | pl f32 | pacc bf16
    const size_t XRED_N = (size_t)BB * INNER * NPIX;
    const size_t FT_N   = (size_t)64 * TOTPIX;
    const size_t TOK_N  = (size_t)BB * NPIX * NCH;
    const size_t HEAD_B = XRED_N * 4 + (FT_N + 2 * TOK_N) * 2;
    int P = 0;
    const int cands[5] = {16, 8, 4, 2, 1};               // KP=9216/P mult of 32 for all
    for (int ci = 0; ci < 5; ++ci) {
        int cp = cands[ci];
        size_t need = HEAD_B + (size_t)BB * cp * NPIX * (4 + NCH * 2);
        if (ws_size >= need) { P = cp; break; }
    }
    if (P == 0) return;

    float*  xred = (float*)d_ws;
    ushort* FT   = (ushort*)(xred + XRED_N);
    ushort* tok  = FT + FT_N;
    ushort* tokT = tok + TOK_N;
    float*  pl   = (float*)(tokT + TOK_N);
    ushort* pacc = (ushort*)(pl + (size_t)BB * P * NPIX);

    k_reduce <<<(TOTPIX + 255) / 256, 256, 0, stream>>>(x, w_red, b_red, xred);
    k_feat   <<<3 * TOTPIX / 256, 256, 0, stream>>>(xred, w_dil, b_dil, FT);
    k_fuse   <<<TOTPIX / 64, 256, 0, stream>>>(FT, w_fuse, b_fuse, tok, tokT);
    k_attn   <<<BB * P * (NPIX / 256), 256, 0, stream>>>(tok, tokT, pl, pacc,
                                                         P, NPIX / P);
    k_combine<<<(TOTPIX * 16 + 255) / 256, 256, 0, stream>>>(x, pl, pacc, out, P);
}